// Round 2
// baseline (482.997 us; speedup 1.0000x reference)
//
#include <hip/hip_runtime.h>
#include <math.h>

#define BB 4
#define TT 4096
#define DDIM 2048
#define PP 256                 // DD_PAIRS
#define MM (BB*TT)             // 16384 rows
#define KKDIM DDIM             // 2048
#define CHUNK 32
#define NCHUNK (TT/CHUNK)      // 128

// ---------------------------------------------------------------------------
// K1: GEMM  delta[m*dstride + doff + n] = sum_k x[m][k] * W[n][k] + bias[n]
// 64x64 tile, 256 threads, 4x4 micro-tile per thread.
// ---------------------------------------------------------------------------
__global__ __launch_bounds__(256) void gemm_k(const float* __restrict__ x,
                                              const float* __restrict__ W,
                                              const float* __restrict__ bias,
                                              float* __restrict__ delta,
                                              int dstride, int doff) {
    __shared__ float As[16][68];   // [k][m], 68 = 64 + 4 pad
    __shared__ float Bs[16][68];   // [k][n]
    const int m0  = blockIdx.x * 64;
    const int n0  = blockIdx.y * 64;
    const int tid = threadIdx.x;
    const int lr  = tid >> 2;        // 0..63
    const int lc  = (tid & 3) << 2;  // 0,4,8,12
    const int tmi = tid & 15;
    const int tni = tid >> 4;

    float acc[4][4] = {};

    for (int k0 = 0; k0 < KKDIM; k0 += 16) {
        float4 a4 = *(const float4*)(x + (size_t)(m0 + lr) * KKDIM + k0 + lc);
        float4 b4 = *(const float4*)(W + (size_t)(n0 + lr) * KKDIM + k0 + lc);
        __syncthreads();
        As[lc + 0][lr] = a4.x; As[lc + 1][lr] = a4.y;
        As[lc + 2][lr] = a4.z; As[lc + 3][lr] = a4.w;
        Bs[lc + 0][lr] = b4.x; Bs[lc + 1][lr] = b4.y;
        Bs[lc + 2][lr] = b4.z; Bs[lc + 3][lr] = b4.w;
        __syncthreads();
        #pragma unroll
        for (int kk = 0; kk < 16; ++kk) {
            float4 av = *(const float4*)&As[kk][tmi * 4];
            float4 bv = *(const float4*)&Bs[kk][tni * 4];
            float am[4] = {av.x, av.y, av.z, av.w};
            float bn[4] = {bv.x, bv.y, bv.z, bv.w};
            #pragma unroll
            for (int i = 0; i < 4; ++i)
                #pragma unroll
                for (int j = 0; j < 4; ++j)
                    acc[i][j] += am[i] * bn[j];
        }
    }

    const float4 b4 = *(const float4*)(bias + n0 + tni * 4);
    #pragma unroll
    for (int i = 0; i < 4; ++i) {
        size_t m = (size_t)(m0 + tmi * 4 + i);
        float4 o;
        o.x = acc[i][0] + b4.x;
        o.y = acc[i][1] + b4.y;
        o.z = acc[i][2] + b4.z;
        o.w = acc[i][3] + b4.w;
        *(float4*)(delta + m * dstride + doff + n0 + tni * 4) = o;
    }
}

// ---------------------------------------------------------------------------
// K2a: per-chunk sums. block = (b, chunk), thread = p.
// ---------------------------------------------------------------------------
__global__ __launch_bounds__(256) void chunksum_k(const float* __restrict__ delta,
                                                  int dstride, int doff,
                                                  float* __restrict__ csum,
                                                  int cstride) {
    const int bc = blockIdx.x;               // 0 .. BB*NCHUNK-1
    const int b  = bc / NCHUNK;
    const int c  = bc % NCHUNK;
    const int p  = threadIdx.x;
    const int tbase = b * TT + c * CHUNK;
    float s = 0.f;
    #pragma unroll 8
    for (int t = 0; t < CHUNK; ++t)
        s += delta[(size_t)(tbase + t) * dstride + doff + p];
    csum[(size_t)bc * cstride + p] = s;
}

// ---------------------------------------------------------------------------
// K2b: in-place exclusive scan of chunk sums along c, per (b,p) chain.
// ---------------------------------------------------------------------------
__global__ __launch_bounds__(256) void scan_k(float* __restrict__ csum, int cstride) {
    const int idx = blockIdx.x * 256 + threadIdx.x;  // 0..1023 = b*PP + p
    const int b = idx >> 8;
    const int p = idx & 255;
    float run = 0.f;
    for (int c = 0; c < NCHUNK; ++c) {
        size_t a = (size_t)(b * NCHUNK + c) * cstride + p;
        float v = csum[a];
        csum[a] = run;
        run += v;
    }
}

// ---------------------------------------------------------------------------
// K3: within-chunk inclusive accumulation + sincos + rotation.
// Writes out columns [0, 512).
// ---------------------------------------------------------------------------
__global__ __launch_bounds__(256) void rotate_k(const float* __restrict__ delta,
                                                int dstride, int doff,
                                                const float* __restrict__ csum,
                                                int cstride,
                                                const float* __restrict__ x,
                                                float* __restrict__ out) {
    const int bc = blockIdx.x;
    const int b  = bc / NCHUNK;
    const int c  = bc % NCHUNK;
    const int p  = threadIdx.x;
    const int tbase = b * TT + c * CHUNK;
    float angle = csum[(size_t)bc * cstride + p];
    for (int t = 0; t < CHUNK; ++t) {
        size_t row = (size_t)(tbase + t);
        angle += delta[row * dstride + doff + p];
        float s, co;
        sincosf(angle, &s, &co);
        float x1 = x[row * DDIM + p];
        float x2 = x[row * DDIM + PP + p];
        out[row * DDIM + p]      = x1 * co - x2 * s;
        out[row * DDIM + PP + p] = x2 * co + x1 * s;
    }
}

// ---------------------------------------------------------------------------
// K4: passthrough copy of columns [512, 2048). Runs LAST.
// grid = (MM/4, 6), 256 threads: each wave copies 64 contiguous float4
// (1 KiB) of one row. Per row: 6 segments x 64 lanes x 4 floats = 1536 cols.
// ---------------------------------------------------------------------------
__global__ __launch_bounds__(256) void copy_k(const float* __restrict__ x,
                                              float* __restrict__ out) {
    const size_t row = (size_t)blockIdx.x * 4 + (threadIdx.x >> 6);
    const int lane = threadIdx.x & 63;
    const int col = 512 + (blockIdx.y * 64 + lane) * 4;   // 512..2044
    const size_t a = row * DDIM + col;
    *(float4*)(out + a) = *(const float4*)(x + a);
}

extern "C" void kernel_launch(void* const* d_in, const int* in_sizes, int n_in,
                              void* d_out, int out_size, void* d_ws, size_t ws_size,
                              hipStream_t stream) {
    const float* x    = (const float*)d_in[0];
    const float* W    = (const float*)d_in[1];
    const float* bias = (const float*)d_in[2];
    float* out = (float*)d_out;

    const size_t delta_elems = (size_t)MM * PP;              // 16 MiB
    const size_t csum_elems  = (size_t)BB * NCHUNK * PP;     // 512 KiB
    const size_t need = (delta_elems + csum_elems) * sizeof(float);

    float* delta; int dstride, doff;
    float* csum;  int cstride;
    if (ws_size >= need) {
        delta   = (float*)d_ws; dstride = PP; doff = 0;
        csum    = (float*)d_ws + delta_elems; cstride = PP;
    } else {
        // Stage deltas in out[:, 512:768) and csum in out[0:512, 768:1024);
        // both are consumed before K4 overwrites columns >= 512.
        delta   = out; dstride = DDIM; doff = 512;
        csum    = out + 768; cstride = DDIM;
    }

    gemm_k<<<dim3(MM / 64, PP / 64), 256, 0, stream>>>(x, W, bias, delta, dstride, doff);
    chunksum_k<<<BB * NCHUNK, 256, 0, stream>>>(delta, dstride, doff, csum, cstride);
    scan_k<<<(BB * PP) / 256, 256, 0, stream>>>(csum, cstride);
    rotate_k<<<BB * NCHUNK, 256, 0, stream>>>(delta, dstride, doff, csum, cstride, x, out);
    copy_k<<<dim3(MM / 4, 6), 256, 0, stream>>>(x, out);
}

// Round 3
// 368.185 us; speedup vs baseline: 1.3118x; 1.3118x over previous
//
#include <hip/hip_runtime.h>
#include <math.h>

#define BB 4
#define TT 4096
#define DDIM 2048
#define PP 256                 // DD_PAIRS
#define MM (BB*TT)             // 16384 rows
#define KKDIM 2048
#define CHUNK 32
#define NCHUNK (TT/CHUNK)      // 128

typedef __attribute__((ext_vector_type(8))) short short8;   // 8 bf16 (4 VGPRs)
typedef __attribute__((ext_vector_type(4))) float f32x4;    // MFMA C/D

__device__ __forceinline__ unsigned short f2bf(float f) {
    unsigned u = __float_as_uint(f);
    u += 0x7FFF + ((u >> 16) & 1);          // round-to-nearest-even
    return (unsigned short)(u >> 16);
}
__device__ __forceinline__ float bf2f(unsigned short h) {
    return __uint_as_float(((unsigned)h) << 16);
}

// ===========================================================================
// K1 (ws path): split-bf16 MFMA GEMM, fused per-chunk column sums.
// delta[m][p] = sum_k x[m][k]*W[p][k] + bias[p]
// Block tile 128(M) x 64(N), BK=32, 256 threads = 4 waves; wave w owns rows
// [w*32, w*32+32) == exactly one cumsum chunk -> shuffle-reduced chunk sums.
// x ~ hi+lo bf16, W ~ hi+lo bf16; 3 MFMA products (drop lo*lo, ~2^-18 rel).
// ===========================================================================
#define LSTR 56    // LDS row stride in bf16 elems: 112 B = 16B-aligned, 2-way max

__global__ __launch_bounds__(256) void gemm_mfma_k(const float* __restrict__ x,
                                                   const float* __restrict__ W,
                                                   const float* __restrict__ bias,
                                                   float* __restrict__ delta,
                                                   float* __restrict__ csum) {
    __shared__ unsigned short Ahi[128 * LSTR];
    __shared__ unsigned short Alo[128 * LSTR];
    __shared__ unsigned short Bhi[64 * LSTR];
    __shared__ unsigned short Blo[64 * LSTR];

    const int n0   = blockIdx.x * 64;
    const int m0   = blockIdx.y * 128;
    const int tid  = threadIdx.x;
    const int w    = tid >> 6;       // wave 0..3
    const int lane = tid & 63;
    const int lm   = lane & 15;      // m (A) / n (B) within 16-tile
    const int ko   = lane >> 4;      // k-octet 0..3  (also C row-quad)

    f32x4 acc[2][4];
    #pragma unroll
    for (int i = 0; i < 2; ++i)
        #pragma unroll
        for (int j = 0; j < 4; ++j) {
            f32x4 z = {0.f, 0.f, 0.f, 0.f};
            acc[i][j] = z;
        }

    for (int k0 = 0; k0 < KKDIM; k0 += 32) {
        // ---- global loads (hoisted before barrier) ----
        float4 av[4], bv[2];
        #pragma unroll
        for (int r = 0; r < 4; ++r) {
            int f = r * 256 + tid;               // 0..1023
            av[r] = *(const float4*)(x + (size_t)(m0 + (f >> 3)) * KKDIM + k0 + ((f & 7) << 2));
        }
        #pragma unroll
        for (int r = 0; r < 2; ++r) {
            int f = r * 256 + tid;               // 0..511
            bv[r] = *(const float4*)(W + (size_t)(n0 + (f >> 3)) * KKDIM + k0 + ((f & 7) << 2));
        }
        __syncthreads();   // previous iter's LDS reads complete
        // ---- convert fp32 -> (hi, lo) bf16, store to LDS ----
        #pragma unroll
        for (int r = 0; r < 4; ++r) {
            int f = r * 256 + tid;
            int idx = (f >> 3) * LSTR + ((f & 7) << 2);
            float4 v = av[r];
            unsigned short h0 = f2bf(v.x), h1 = f2bf(v.y), h2 = f2bf(v.z), h3 = f2bf(v.w);
            unsigned short l0 = f2bf(v.x - bf2f(h0)), l1 = f2bf(v.y - bf2f(h1));
            unsigned short l2 = f2bf(v.z - bf2f(h2)), l3 = f2bf(v.w - bf2f(h3));
            uint2 hp = { (unsigned)h0 | ((unsigned)h1 << 16), (unsigned)h2 | ((unsigned)h3 << 16) };
            uint2 lp = { (unsigned)l0 | ((unsigned)l1 << 16), (unsigned)l2 | ((unsigned)l3 << 16) };
            *(uint2*)&Ahi[idx] = hp;
            *(uint2*)&Alo[idx] = lp;
        }
        #pragma unroll
        for (int r = 0; r < 2; ++r) {
            int f = r * 256 + tid;
            int idx = (f >> 3) * LSTR + ((f & 7) << 2);
            float4 v = bv[r];
            unsigned short h0 = f2bf(v.x), h1 = f2bf(v.y), h2 = f2bf(v.z), h3 = f2bf(v.w);
            unsigned short l0 = f2bf(v.x - bf2f(h0)), l1 = f2bf(v.y - bf2f(h1));
            unsigned short l2 = f2bf(v.z - bf2f(h2)), l3 = f2bf(v.w - bf2f(h3));
            uint2 hp = { (unsigned)h0 | ((unsigned)h1 << 16), (unsigned)h2 | ((unsigned)h3 << 16) };
            uint2 lp = { (unsigned)l0 | ((unsigned)l1 << 16), (unsigned)l2 | ((unsigned)l3 << 16) };
            *(uint2*)&Bhi[idx] = hp;
            *(uint2*)&Blo[idx] = lp;
        }
        __syncthreads();
        // ---- fragment reads + MFMA ----
        short8 ah[2], al[2], bh[4], bl[4];
        #pragma unroll
        for (int mt = 0; mt < 2; ++mt) {
            int idx = (w * 32 + mt * 16 + lm) * LSTR + ko * 8;
            ah[mt] = *(const short8*)&Ahi[idx];
            al[mt] = *(const short8*)&Alo[idx];
        }
        #pragma unroll
        for (int nt = 0; nt < 4; ++nt) {
            int idx = (nt * 16 + lm) * LSTR + ko * 8;
            bh[nt] = *(const short8*)&Bhi[idx];
            bl[nt] = *(const short8*)&Blo[idx];
        }
        #pragma unroll
        for (int mt = 0; mt < 2; ++mt)
            #pragma unroll
            for (int nt = 0; nt < 4; ++nt) {
                f32x4 c = acc[mt][nt];
                c = __builtin_amdgcn_mfma_f32_16x16x32_bf16(ah[mt], bh[nt], c, 0, 0, 0);
                c = __builtin_amdgcn_mfma_f32_16x16x32_bf16(ah[mt], bl[nt], c, 0, 0, 0);
                c = __builtin_amdgcn_mfma_f32_16x16x32_bf16(al[mt], bh[nt], c, 0, 0, 0);
                acc[mt][nt] = c;
            }
    }

    // ---- epilogue: bias, store delta, fused chunk sums ----
    float bsv[4];
    #pragma unroll
    for (int nt = 0; nt < 4; ++nt) bsv[nt] = bias[n0 + nt * 16 + lm];

    float cs[4] = {0.f, 0.f, 0.f, 0.f};
    #pragma unroll
    for (int mt = 0; mt < 2; ++mt)
        #pragma unroll
        for (int nt = 0; nt < 4; ++nt)
            #pragma unroll
            for (int r = 0; r < 4; ++r) {
                float val = acc[mt][nt][r] + bsv[nt];
                int m = m0 + w * 32 + mt * 16 + ko * 4 + r;
                delta[(size_t)m * PP + n0 + nt * 16 + lm] = val;
                cs[nt] += val;
            }
    #pragma unroll
    for (int nt = 0; nt < 4; ++nt) {
        float s = cs[nt];
        s += __shfl_xor(s, 16);
        s += __shfl_xor(s, 32);
        if (lane < 16)
            csum[(size_t)(m0 / CHUNK + w) * PP + n0 + nt * 16 + lane] = s;
    }
}

// ===========================================================================
// K2: exclusive scan of chunk sums along c per (b,p) chain, unroll 8 so the
// 8 loads of a group pipeline (independent of the running sum).
// ===========================================================================
__global__ __launch_bounds__(256) void scan_k(float* __restrict__ csum, int cstride) {
    const int idx = blockIdx.x * 256 + threadIdx.x;  // 0..1023 = b*PP + p
    const int b = idx >> 8;
    const int p = idx & 255;
    float run = 0.f;
    for (int c0 = 0; c0 < NCHUNK; c0 += 8) {
        float v[8];
        #pragma unroll
        for (int j = 0; j < 8; ++j)
            v[j] = csum[(size_t)(b * NCHUNK + c0 + j) * cstride + p];
        #pragma unroll
        for (int j = 0; j < 8; ++j) {
            float t = v[j];
            csum[(size_t)(b * NCHUNK + c0 + j) * cstride + p] = run;
            run += t;
        }
    }
}

// ===========================================================================
// K3 (ws path): rotation + passthrough copy fused. Block = one chunk.
// ===========================================================================
__global__ __launch_bounds__(256) void rotate_copy_k(const float* __restrict__ delta,
                                                     const float* __restrict__ csum,
                                                     const float* __restrict__ x,
                                                     float* __restrict__ out) {
    const int bc = blockIdx.x;            // 0..511
    const int p  = threadIdx.x;
    const int tbase = bc * CHUNK;         // global row base
    float angle = csum[(size_t)bc * PP + p];
    for (int t = 0; t < CHUNK; ++t) {
        size_t row = (size_t)(tbase + t);
        angle += delta[row * PP + p];
        float s, co;
        sincosf(angle, &s, &co);
        float x1 = x[row * DDIM + p];
        float x2 = x[row * DDIM + PP + p];
        out[row * DDIM + p]      = x1 * co - x2 * s;
        out[row * DDIM + PP + p] = x2 * co + x1 * s;
    }
    // copy cols [512, 2048) for the same 32 rows; 2 rows x 128 lanes per pass
    const int half = p >> 7;              // 0/1
    const int q    = p & 127;
    for (int rp = 0; rp < 16; ++rp) {
        size_t row = (size_t)(tbase + rp * 2 + half);
        const float4* src = (const float4*)(x + row * DDIM + 512);
        float4*       dst = (float4*)(out + row * DDIM + 512);
        dst[q]       = src[q];
        dst[q + 128] = src[q + 128];
        dst[q + 256] = src[q + 256];
    }
}

// ===========================================================================
// Fallback path kernels (ws too small) — round-2 verified fp32 pipeline.
// ===========================================================================
__global__ __launch_bounds__(256) void gemm_k(const float* __restrict__ x,
                                              const float* __restrict__ W,
                                              const float* __restrict__ bias,
                                              float* __restrict__ delta,
                                              int dstride, int doff) {
    __shared__ float As[16][68];
    __shared__ float Bs[16][68];
    const int m0  = blockIdx.x * 64;
    const int n0  = blockIdx.y * 64;
    const int tid = threadIdx.x;
    const int lr  = tid >> 2;
    const int lc  = (tid & 3) << 2;
    const int tmi = tid & 15;
    const int tni = tid >> 4;
    float acc[4][4] = {};
    for (int k0 = 0; k0 < KKDIM; k0 += 16) {
        float4 a4 = *(const float4*)(x + (size_t)(m0 + lr) * KKDIM + k0 + lc);
        float4 b4 = *(const float4*)(W + (size_t)(n0 + lr) * KKDIM + k0 + lc);
        __syncthreads();
        As[lc + 0][lr] = a4.x; As[lc + 1][lr] = a4.y;
        As[lc + 2][lr] = a4.z; As[lc + 3][lr] = a4.w;
        Bs[lc + 0][lr] = b4.x; Bs[lc + 1][lr] = b4.y;
        Bs[lc + 2][lr] = b4.z; Bs[lc + 3][lr] = b4.w;
        __syncthreads();
        #pragma unroll
        for (int kk = 0; kk < 16; ++kk) {
            float4 av = *(const float4*)&As[kk][tmi * 4];
            float4 bv = *(const float4*)&Bs[kk][tni * 4];
            float am[4] = {av.x, av.y, av.z, av.w};
            float bn[4] = {bv.x, bv.y, bv.z, bv.w};
            #pragma unroll
            for (int i = 0; i < 4; ++i)
                #pragma unroll
                for (int j = 0; j < 4; ++j)
                    acc[i][j] += am[i] * bn[j];
        }
    }
    const float4 b4 = *(const float4*)(bias + n0 + tni * 4);
    #pragma unroll
    for (int i = 0; i < 4; ++i) {
        size_t m = (size_t)(m0 + tmi * 4 + i);
        float4 o;
        o.x = acc[i][0] + b4.x; o.y = acc[i][1] + b4.y;
        o.z = acc[i][2] + b4.z; o.w = acc[i][3] + b4.w;
        *(float4*)(delta + m * dstride + doff + n0 + tni * 4) = o;
    }
}

__global__ __launch_bounds__(256) void chunksum_k(const float* __restrict__ delta,
                                                  int dstride, int doff,
                                                  float* __restrict__ csum, int cstride) {
    const int bc = blockIdx.x;
    const int b  = bc / NCHUNK;
    const int c  = bc % NCHUNK;
    const int p  = threadIdx.x;
    const int tbase = b * TT + c * CHUNK;
    float s = 0.f;
    #pragma unroll 8
    for (int t = 0; t < CHUNK; ++t)
        s += delta[(size_t)(tbase + t) * dstride + doff + p];
    csum[(size_t)bc * cstride + p] = s;
}

__global__ __launch_bounds__(256) void rotate_k(const float* __restrict__ delta,
                                                int dstride, int doff,
                                                const float* __restrict__ csum, int cstride,
                                                const float* __restrict__ x,
                                                float* __restrict__ out) {
    const int bc = blockIdx.x;
    const int b  = bc / NCHUNK;
    const int c  = bc % NCHUNK;
    const int p  = threadIdx.x;
    const int tbase = b * TT + c * CHUNK;
    float angle = csum[(size_t)bc * cstride + p];
    for (int t = 0; t < CHUNK; ++t) {
        size_t row = (size_t)(tbase + t);
        angle += delta[row * dstride + doff + p];
        float s, co;
        sincosf(angle, &s, &co);
        float x1 = x[row * DDIM + p];
        float x2 = x[row * DDIM + PP + p];
        out[row * DDIM + p]      = x1 * co - x2 * s;
        out[row * DDIM + PP + p] = x2 * co + x1 * s;
    }
}

__global__ __launch_bounds__(256) void copy_k(const float* __restrict__ x,
                                              float* __restrict__ out) {
    const size_t row = (size_t)blockIdx.x * 4 + (threadIdx.x >> 6);
    const int lane = threadIdx.x & 63;
    const int col = 512 + (blockIdx.y * 64 + lane) * 4;
    const size_t a = row * DDIM + col;
    *(float4*)(out + a) = *(const float4*)(x + a);
}

extern "C" void kernel_launch(void* const* d_in, const int* in_sizes, int n_in,
                              void* d_out, int out_size, void* d_ws, size_t ws_size,
                              hipStream_t stream) {
    const float* x    = (const float*)d_in[0];
    const float* W    = (const float*)d_in[1];
    const float* bias = (const float*)d_in[2];
    float* out = (float*)d_out;

    const size_t delta_elems = (size_t)MM * PP;
    const size_t csum_elems  = (size_t)BB * NCHUNK * PP;
    const size_t need = (delta_elems + csum_elems) * sizeof(float);

    if (ws_size >= need) {
        float* delta = (float*)d_ws;
        float* csum  = (float*)d_ws + delta_elems;
        gemm_mfma_k<<<dim3(PP / 64, MM / 128), 256, 0, stream>>>(x, W, bias, delta, csum);
        scan_k<<<(BB * PP) / 256, 256, 0, stream>>>(csum, PP);
        rotate_copy_k<<<BB * NCHUNK, 256, 0, stream>>>(delta, csum, x, out);
    } else {
        // fallback staging in d_out (verified round-2 path)
        float* delta = out; const int dstride = DDIM, doff = 512;
        float* csum  = out + 768; const int cstride = DDIM;
        gemm_k<<<dim3(MM / 64, PP / 64), 256, 0, stream>>>(x, W, bias, delta, dstride, doff);
        chunksum_k<<<BB * NCHUNK, 256, 0, stream>>>(delta, dstride, doff, csum, cstride);
        scan_k<<<(BB * PP) / 256, 256, 0, stream>>>(csum, cstride);
        rotate_k<<<BB * NCHUNK, 256, 0, stream>>>(delta, dstride, doff, csum, cstride, x, out);
        copy_k<<<dim3(MM / 4, 6), 256, 0, stream>>>(x, out);
    }
}